// Round 1
// 282.332 us; speedup vs baseline: 1.0578x; 1.0578x over previous
//
#include <hip/hip_runtime.h>
#include <hip/hip_fp16.h>

typedef float f4 __attribute__((ext_vector_type(4)));
typedef short s8 __attribute__((ext_vector_type(8)));
typedef unsigned short u16x4 __attribute__((ext_vector_type(4)));
typedef unsigned short u16x8 __attribute__((ext_vector_type(8)));

// ---- ws layout (bytes) ----
// embB   : 1 MiB    .. 5 MiB   (4096*512 bf16)
// rbT    : 5 MiB    .. 37 MiB  (64*512*512 bf16, [n][o][i])
// gemmT  : 37 MiB   .. 53 MiB  (2 slices of 512*4096 f32, [o][b])

__device__ __forceinline__ unsigned short f2bf(float f) {
    unsigned int u = __float_as_uint(f);
    unsigned int r = (u + 0x7fffu + ((u >> 16) & 1u)) >> 16;
    return (unsigned short)r;
}

// blocks [0,2048): emb f32->bf16. blocks [2048, 2048+4096): rbT transpose, 64x64 tiles.
__global__ __launch_bounds__(256) void prep_kernel(const float* __restrict__ emb,
                                                   unsigned short* __restrict__ embB,
                                                   const float* __restrict__ rb,
                                                   unsigned short* __restrict__ rbT) {
    int bid = blockIdx.x;
    int t = threadIdx.x;
    if (bid < 2048) {
        int g = (bid * 256 + t) * 4;
        f4 v = *(const f4*)(emb + g);
        u16x4 o;
        o[0] = f2bf(v[0]); o[1] = f2bf(v[1]); o[2] = f2bf(v[2]); o[3] = f2bf(v[3]);
        *(u16x4*)(embB + g) = o;
        return;
    }
    __shared__ float tl[64][65];
    int b2 = bid - 2048;
    int n = b2 >> 6;
    int rem = b2 & 63;
    int i0 = (rem & 7) * 64, o0 = (rem >> 3) * 64;
    int oq = t & 15, ir = t >> 4;
#pragma unroll
    for (int k = 0; k < 4; k++) {
        int r = ir + 16 * k;
        f4 v = *(const f4*)(rb + (size_t)(n * 512 + i0 + r) * 512 + o0 + oq * 4);
        tl[r][oq * 4 + 0] = v[0]; tl[r][oq * 4 + 1] = v[1];
        tl[r][oq * 4 + 2] = v[2]; tl[r][oq * 4 + 3] = v[3];
    }
    __syncthreads();
    int ic = t & 7, or0 = t >> 3;
#pragma unroll
    for (int k = 0; k < 2; k++) {
        int orow = or0 + 32 * k;
        u16x8 w;
#pragma unroll
        for (int j = 0; j < 8; j++) w[j] = f2bf(tl[ic * 8 + j][orow]);
        *(u16x8*)(rbT + (size_t)(n * 512 + o0 + orow) * 512 + i0 + ic * 8) = w;
    }
}

// Main fused GEMM, v2: K-chunks of 64 (embF = 8 s8 -> guaranteed register-resident),
// register-pipelined A-fragments + att (distance-1 prefetch into a second reg set),
// counted waits only (lgkmcnt(2) WAR, vmcnt(2) tile-ready), bias folded into epilogue.
// LDS = 2x8KiB dbuf + 4KiB packed-f16 att = 20.5 KiB -> comfortably 4 blocks/CU.
// VGPR budget ~106 under __launch_bounds__(256,4) (cap 128).
__global__ __launch_bounds__(256, 4) void gemm_fold(const unsigned short* __restrict__ embB,
                                                    const unsigned short* __restrict__ rbT,
                                                    const int* __restrict__ ids,
                                                    const float* __restrict__ rel_att,
                                                    const float* __restrict__ relb,
                                                    float* __restrict__ gemmT) {
    __shared__ unsigned short bS[2][64 * 64];   // [buf][o_local*64 + i_local], 16B-chunk xor-swizzle
    __shared__ unsigned int attH[32][32];       // [n][h] = half2(att[m0+h], att[m0+h+32])

    const int t = threadIdx.x;
    const int wv = t >> 6;
    const int ln = t & 63;
    const int q  = ln >> 4;     // quad 0..3
    const int lm = ln & 15;
    const int g  = blockIdx.x;
    const int o0 = (g & 7) * 64;                  // fastest -> XCD-aligned o slice
    const int m0 = ((g >> 3) & 63) * 64;
    const int nz = g >> 9;                        // n-half 0/1
    const int nbase = nz * 32;

    // lane constants
    const int lr = ln >> 3;                       // stage: row-in-chunk 0..7
    const int lc = ln & 7;                        // stage: 16B slot 0..7
    const int loff = lr * 512 + ((lc ^ lr) * 8);  // global element offset (lane part)
    const int arow = wv * 16 + lm;                // this wave's A row for its lm
    const int aoff0 = arow * 128 + (((0 * 4 + q) ^ (lm & 7)) * 16);
    const int aoff1 = arow * 128 + (((1 * 4 + q) ^ (lm & 7)) * 16);

    // async stage of one 64o x 64i bf16 tile; wave's 2 chunks cover its own rows
    // [wv*16, wv*16+16) -> wave-private producer/consumer, no block barrier in K-loop.
    auto stage = [&](int sx, int buf) {
        const int ic = sx >> 5;
        const int n  = nbase + (sx & 31);
        const unsigned short* gb = rbT + (size_t)n * 262144 + (size_t)o0 * 512 + ic * 64 + loff;
#pragma unroll
        for (int j = 0; j < 2; j++) {
            const int c = wv * 2 + j;             // chunk 0..7
            const unsigned short* gp = gb + c * 4096;   // +8 rows per chunk
            void* l = (char*)(&bS[buf][0]) + c * 1024;
            __builtin_amdgcn_global_load_lds((const __attribute__((address_space(1))) void*)gp,
                                             (__attribute__((address_space(3))) void*)l,
                                             16, 0, 0);
        }
    };

    stage(0, 0);
    stage(1, 1);

    // att tile gathered via ids, packed to f16 pairs (m, m+32)
#pragma unroll
    for (int k = 0; k < 4; k++) {
        int e = t + 256 * k;                      // 0..1023
        int n = e >> 5, h = e & 31;
        float a0 = rel_att[(size_t)ids[m0 + h] * 64 + nbase + n];
        float a1 = rel_att[(size_t)ids[m0 + h + 32] * 64 + nbase + n];
        __half2 hp = __floats2half2_rn(a0, a1);
        attH[n][h] = *(unsigned int*)&hp;
    }
    __syncthreads();                              // the ONLY block barrier

    const f4 z = {0.f, 0.f, 0.f, 0.f};
    f4 acc0 = z, acc1 = z, acc2 = z, acc3 = z;
    s8 embF[2][4];                                // 8 s8 = 32 VGPR, resident across n-loop

    asm volatile("s_waitcnt vmcnt(2)" ::: "memory");   // tile 0 landed
    const char* bp0 = (const char*)&bS[0][0];
    s8 cA0 = *(const s8*)(bp0 + aoff0);
    s8 cA1 = *(const s8*)(bp0 + aoff1);
    unsigned int aA0 = attH[0][lm], aA1 = attH[0][lm + 16];
    s8 cB0, cB1;
    unsigned int aB0, aB1;

    // steady-state invariant at entry: cur frags (c0,c1,ca*) issued last iter;
    // outstanding LDS = {cur aF(2), cur att(2)}; outstanding VMEM = stage(s+1) [2 loads].
    auto iterate = [&](int s, int bufc, s8& c0, s8& c1, unsigned int& ca0, unsigned int& ca1,
                       s8& n0, s8& n1, unsigned int& na0, unsigned int& na1) {
        // cur A-frags complete (att may still be in flight) -> WAR vs restage resolved
        asm volatile("s_waitcnt lgkmcnt(2)" ::: "memory");
        const int nl = s & 31;
        if (nl == 0) {
            // emb fragments for this i-chunk; issued BEFORE stage so the counted
            // vmcnt below drains them without collapsing the staging window.
            const int ic = s >> 5;
            const unsigned short* eb = embB + (size_t)(m0 + lm) * 512 + ic * 64 + q * 8;
#pragma unroll
            for (int ks = 0; ks < 2; ks++)
#pragma unroll
                for (int ms = 0; ms < 4; ms++)
                    embF[ks][ms] = *(const s8*)(eb + ms * 8192 + ks * 32);
        }
        if (s < 254) {
            stage(s + 2, bufc);                   // overwrite cur buffer (frags safe in regs)
            asm volatile("s_waitcnt vmcnt(2)" ::: "memory");  // tile s+1 resident, s+2 in flight
        } else {
            asm volatile("s_waitcnt vmcnt(0)" ::: "memory");  // tail: no s+2 issued
        }
        // prefetch next tile's fragments + att into the alternate register set
        const char* bn = (const char*)&bS[bufc ^ 1][0];
        n0 = *(const s8*)(bn + aoff0);
        n1 = *(const s8*)(bn + aoff1);
        const int nn = (nl + 1) & 31;
        na0 = attH[nn][lm];
        na1 = attH[nn][lm + 16];
        __builtin_amdgcn_s_setprio(1);
        f4 an0 = __builtin_amdgcn_mfma_f32_16x16x32_bf16(c0, embF[0][0], z, 0, 0, 0);
        f4 an1 = __builtin_amdgcn_mfma_f32_16x16x32_bf16(c0, embF[0][1], z, 0, 0, 0);
        f4 an2 = __builtin_amdgcn_mfma_f32_16x16x32_bf16(c0, embF[0][2], z, 0, 0, 0);
        f4 an3 = __builtin_amdgcn_mfma_f32_16x16x32_bf16(c0, embF[0][3], z, 0, 0, 0);
        an0 = __builtin_amdgcn_mfma_f32_16x16x32_bf16(c1, embF[1][0], an0, 0, 0, 0);
        an1 = __builtin_amdgcn_mfma_f32_16x16x32_bf16(c1, embF[1][1], an1, 0, 0, 0);
        an2 = __builtin_amdgcn_mfma_f32_16x16x32_bf16(c1, embF[1][2], an2, 0, 0, 0);
        an3 = __builtin_amdgcn_mfma_f32_16x16x32_bf16(c1, embF[1][3], an3, 0, 0, 0);
        __builtin_amdgcn_s_setprio(0);
        float2 f0 = __half22float2(*(const __half2*)&ca0);
        float2 f1 = __half22float2(*(const __half2*)&ca1);
        acc0 += f0.x * an0;
        acc1 += f1.x * an1;
        acc2 += f0.y * an2;
        acc3 += f1.y * an3;
    };

    for (int s = 0; s < 256; s += 2) {
        iterate(s,     0, cA0, cA1, aA0, aA1, cB0, cB1, aB0, aB1);
        iterate(s + 1, 1, cB0, cB1, aB0, aB1, cA0, cA1, aA0, aA1);
    }

    // bias epilogue: acc[ms][r] += sum_{n in half} att(n, m(ms)) * relb[nbase+n][o(r)]
    // (relb f4 is wave-broadcast: o depends only on wv,q,r)
    const float* rbb = relb + (size_t)nbase * 512 + o0 + wv * 16 + q * 4;
#pragma unroll 4
    for (int n = 0; n < 32; n++) {
        unsigned int p0 = attH[n][lm], p1 = attH[n][lm + 16];
        float2 f0 = __half22float2(*(const __half2*)&p0);
        float2 f1 = __half22float2(*(const __half2*)&p1);
        f4 rb4 = *(const f4*)(rbb + (size_t)n * 512);
        acc0 += f0.x * rb4;
        acc1 += f1.x * rb4;
        acc2 += f0.y * rb4;
        acc3 += f1.y * rb4;
    }

    // epilogue: D[row=o][col=m] into this half's slice
    float* gT = gemmT + (size_t)nz * 512 * 4096;
    const int ob = o0 + wv * 16 + q * 4;
    const int mm = m0 + lm;
#pragma unroll
    for (int r = 0; r < 4; r++) {
        gT[(size_t)(ob + r) * 4096 + mm +  0] = acc0[r];
        gT[(size_t)(ob + r) * 4096 + mm + 16] = acc1[r];
        gT[(size_t)(ob + r) * 4096 + mm + 32] = acc2[r];
        gT[(size_t)(ob + r) * 4096 + mm + 48] = acc3[r];
    }
}

// LayerNorm over o (512) per b: v = g0 + g1 (bias already folded into gemmT).
// 8 b per block, grid 512.
__global__ __launch_bounds__(256) void ln_kernel(const float* __restrict__ g0,
                                                 const float* __restrict__ g1,
                                                 float* __restrict__ out) {
    __shared__ float S[512][9];
    int t = threadIdx.x;
    int b0 = blockIdx.x * 8;
#pragma unroll
    for (int p = 0; p < 4; p++) {
        int r = p * 128 + (t >> 1);
        int cb = (t & 1) * 4;
        f4 a = *(const f4*)(g0 + (size_t)r * 4096 + b0 + cb);
        f4 b = *(const f4*)(g1 + (size_t)r * 4096 + b0 + cb);
        f4 v = a + b;
        S[r][cb + 0] = v[0]; S[r][cb + 1] = v[1]; S[r][cb + 2] = v[2]; S[r][cb + 3] = v[3];
    }
    __syncthreads();
    int b = t >> 5, j = t & 31;
    float s1 = 0.f, s2 = 0.f;
#pragma unroll
    for (int k = 0; k < 16; k++) {
        float v = S[j + 32 * k][b];
        s1 += v; s2 += v * v;
    }
#pragma unroll
    for (int off = 16; off; off >>= 1) {
        s1 += __shfl_down(s1, off, 32);
        s2 += __shfl_down(s2, off, 32);
    }
    s1 = __shfl(s1, (t & 63) & ~31, 64);
    s2 = __shfl(s2, (t & 63) & ~31, 64);
    float mu = s1 * (1.f / 512.f);
    float var = s2 * (1.f / 512.f) - mu * mu;
    float rs = rsqrtf(var + 1e-5f);
#pragma unroll
    for (int k = 0; k < 16; k++) {
        int o = j + 32 * k;
        out[(size_t)(b0 + b) * 512 + o] = (S[o][b] - mu) * rs;
    }
}

extern "C" void kernel_launch(void* const* d_in, const int* in_sizes, int n_in,
                              void* d_out, int out_size, void* d_ws, size_t ws_size,
                              hipStream_t stream) {
    (void)in_sizes; (void)n_in; (void)out_size; (void)ws_size;
    const float* emb      = (const float*)d_in[0];
    const int*   proj_ids = (const int*)d_in[1];
    const float* rel_att  = (const float*)d_in[2];
    const float* rel_base = (const float*)d_in[3];
    const float* rel_bias = (const float*)d_in[4];
    float* out = (float*)d_out;

    char* w = (char*)d_ws;
    unsigned short* embB  = (unsigned short*)(w + (1u << 20));
    unsigned short* rbT   = (unsigned short*)(w + 5u * (1u << 20));
    float*          gemmT = (float*)(w + 37u * (1u << 20));   // 2 slices of 8 MiB
    float*          g1    = gemmT + (size_t)512 * 4096;

    prep_kernel<<<dim3(2048 + 4096), dim3(256), 0, stream>>>(emb, embB, rel_base, rbT);
    gemm_fold<<<dim3(1024), dim3(256), 0, stream>>>(embB, rbT, proj_ids, rel_att, rel_bias, gemmT);
    ln_kernel<<<dim3(512), dim3(256), 0, stream>>>(gemmT, g1, out);
}